// Round 2
// baseline (289.199 us; speedup 1.0000x reference)
//
#include <hip/hip_runtime.h>

typedef unsigned short u16;
typedef unsigned int u32;
typedef __attribute__((ext_vector_type(8))) short bf16x8;
typedef __attribute__((ext_vector_type(4))) short bf16x4;
typedef __attribute__((ext_vector_type(4))) float f32x4;

#define MFMA16(a, b, c) __builtin_amdgcn_mfma_f32_16x16x32_bf16(a, b, c, 0, 0, 0)
// K=16 bf16 MFMA (gfx90a-lineage "_1k" builtin, valid on gfx950 per ISA §10).
#define MFMAK16(a, b, c) __builtin_amdgcn_mfma_f32_16x16x16bf16_1k(a, b, c, 0, 0, 0)

__device__ __forceinline__ float hw_exp2(float x) { return __builtin_amdgcn_exp2f(x); }

__device__ __forceinline__ u16 f2bf(float f) {
    union { float f; u32 i; } v; v.f = f;
    u32 x = v.i;
    return (u16)((x + 0x7FFFu + ((x >> 16) & 1u)) >> 16);
}

// Device-scope grid barrier. Safe because grid(512) x __launch_bounds__(256,2)
// guarantees 2 blocks/CU x 256 CUs co-resident (VGPR capped at 256, LDS 32KB).
// Counters zeroed per-launch by hipMemsetAsync. atomicAdd(...,0) polling goes to
// the coherence point (device scope), so no stale per-XCD L2 reads.
__device__ __forceinline__ void grid_barrier(u32* bar, int slot) {
    __syncthreads();
    if (threadIdx.x == 0) {
        __threadfence();                 // release: make this block's stores visible
        atomicAdd(&bar[slot], 1u);
        while (atomicAdd(&bar[slot], 0u) < 512u) __builtin_amdgcn_s_sleep(2);
        __threadfence();                 // acquire: see all other blocks' stores
    }
    __syncthreads();
}

// ---------------- fused persistent kernel: prep -> qkv -> attn -> out ----------------
__global__ __launch_bounds__(256, 2) void k_fused(
    const float* __restrict__ x, const float* __restrict__ wqkv,
    const float* __restrict__ btab, const float* __restrict__ wout,
    const float* __restrict__ bout, float* __restrict__ out,
    u16* __restrict__ wqkvT, u16* __restrict__ woutT,
    u16* __restrict__ qkv, float* __restrict__ stab,
    u16* __restrict__ xb, u32* __restrict__ bar) {

    __shared__ __align__(16) u16 smem[16384];  // 32 KB, unioned across phases
    const int bid = blockIdx.x, tid = threadIdx.x;
    const int wave = tid >> 6, lane = tid & 63, quad = lane >> 4, ql = lane & 15;

    // ================= P0: prep (2112 virtual units over 512 blocks) =================
    {
        const float QSCALE2 = 0.2550566756538019f;  // 32^-0.5 * log2(e)
        const float LOG2E = 1.4426950408889634f;
        for (int u = bid; u < 2112; u += 512) {
            if (u < 1024) {
                int base = u * 2048 + tid * 8;
                float4 a = *(const float4*)(x + base);
                float4 b = *(const float4*)(x + base + 4);
                uint4 r;
                r.x = f2bf(a.x) | ((u32)f2bf(a.y) << 16);
                r.y = f2bf(a.z) | ((u32)f2bf(a.w) << 16);
                r.z = f2bf(b.x) | ((u32)f2bf(b.y) << 16);
                r.w = f2bf(b.z) | ((u32)f2bf(b.w) << 16);
                *(uint4*)(xb + base) = r;
            } else if (u < 1792) {
                int idx = (u - 1024) * 256 + tid;
                int n = idx >> 8, kk = idx & 255;
                float sc = (n < 256) ? QSCALE2 : 1.0f;
                wqkvT[idx] = f2bf(wqkv[kk * 768 + n] * sc);
            } else if (u < 2048) {
                int idx = (u - 1792) * 256 + tid;
                int n = idx >> 8, kk = idx & 255;
                woutT[idx] = f2bf(wout[kk * 256 + n]);
            } else {
                int idx = (u - 2048) * 256 + tid;  // < 16384
                stab[idx] = btab[idx] * LOG2E;
            }
        }
    }
    grid_barrier(bar, 0);

    // ================= P1: qkv = xb @ w_qkv (768 units, 2 rounds) =================
    for (int u = bid; u < 768; u += 512) {
        const int bx = u & 63, by = u >> 6;
        u16* slds = smem;  // [128][68] or [64][136]
        const int mbase = bx * 128 + (wave & 1) * 64;
        const int nbase = by * 64 + (wave >> 1) * 32;
        f32x4 acc[4][2];
#pragma unroll
        for (int i = 0; i < 4; ++i)
#pragma unroll
            for (int j = 0; j < 2; ++j) acc[i][j] = (f32x4){0.f, 0.f, 0.f, 0.f};
#pragma unroll
        for (int ks = 0; ks < 8; ++ks) {
            bf16x8 af[4], bfm[2];
#pragma unroll
            for (int ms = 0; ms < 4; ++ms)
                af[ms] = *(const bf16x8*)(xb + (size_t)(mbase + ms * 16 + ql) * 256 + ks * 32 + quad * 8);
#pragma unroll
            for (int ns = 0; ns < 2; ++ns)
                bfm[ns] = *(const bf16x8*)(wqkvT + (size_t)(nbase + ns * 16 + ql) * 256 + ks * 32 + quad * 8);
#pragma unroll
            for (int ms = 0; ms < 4; ++ms)
#pragma unroll
                for (int ns = 0; ns < 2; ++ns)
                    acc[ms][ns] = MFMA16(af[ms], bfm[ns], acc[ms][ns]);
        }

        const int t = (by * 64) >> 8;  // 0=Q, 1=K, 2=V (uniform per unit)
        if (t < 2) {
            const int rowb = (wave & 1) * 64, colb = (wave >> 1) * 32;
#pragma unroll
            for (int ms = 0; ms < 4; ++ms)
#pragma unroll
                for (int ns = 0; ns < 2; ++ns)
#pragma unroll
                    for (int r = 0; r < 4; ++r)
                        slds[(rowb + ms * 16 + quad * 4 + r) * 68 + colb + ns * 16 + ql] =
                            f2bf(acc[ms][ns][r]);
            __syncthreads();
            u16* base = qkv + (size_t)t * 2097152;
#pragma unroll
            for (int p = 0; p < 8; ++p) {
                int c = p * 256 + tid;
                int row = c >> 4, ch = c & 15;
                uint2 w = *(const uint2*)&slds[row * 68 + ch * 4];
                int n = bx * 128 + row;
                int col = by * 64 + ch * 4;
                int h = (col & 255) >> 5, d = col & 31;
                *(uint2*)(base + ((size_t)((n >> 11) * 8 + h) * 2048 + (n & 2047)) * 32 + d) = w;
            }
        } else {
            const int hl = wave >> 1, nb = (wave & 1) * 64;
#pragma unroll
            for (int ms = 0; ms < 4; ++ms)
#pragma unroll
                for (int ns = 0; ns < 2; ++ns) {
                    u16 e0 = f2bf(acc[ms][ns][0]), e1 = f2bf(acc[ms][ns][1]);
                    u16 e2 = f2bf(acc[ms][ns][2]), e3 = f2bf(acc[ms][ns][3]);
                    uint2 pp; pp.x = e0 | ((u32)e1 << 16); pp.y = e2 | ((u32)e3 << 16);
                    *(uint2*)&slds[(hl * 32 + ns * 16 + ql) * 136 + nb + ms * 16 + quad * 4] = pp;
                }
            __syncthreads();
            u16* vbase = qkv + (size_t)2 * 2097152;
#pragma unroll
            for (int p = 0; p < 4; ++p) {
                int c = p * 256 + tid;
                int row = c >> 4, ch = c & 15;
                bf16x8 w = *(const bf16x8*)&slds[row * 136 + ch * 8];
                int n0 = bx * 128 + ch * 8;
                int h = (by & 3) * 2 + (row >> 5), d = row & 31;
                *(bf16x8*)(vbase + (size_t)((n0 >> 11) * 8 + h) * 65536 +
                           (size_t)d * 2048 + (n0 & 2047)) = w;
            }
        }
        __syncthreads();  // protect slds before next unit reuses it
    }
    grid_barrier(bar, 1);

    // ================= P2: flash attention (exactly 512 blocks) =================
    {
        const u16* q = qkv;
        const u16* k = qkv + 2097152;
        const u16* vT = qkv + 2 * 2097152;
        u16* att = qkv;  // overwrite Q region in place
        const int bh = bid & 31, qt = bid >> 5;

        // smem union: kbuf = smem[0..8191], vbuf = smem[8192..16383]
#define KB(BUF, T) (smem + (BUF) * 4096 + (T) * 2048)
#define VB(BUF, T) (smem + 8192 + (BUF) * 4096 + (T) * 2048)

        const u16* kbh = k + (size_t)bh * 65536;
        const u16* vbh = vT + (size_t)bh * 65536;  // [32 d][2048 n]

        const int krow = wave * 16 + (lane >> 2);
        const u16* kg = kbh + krow * 32 + ((((lane & 3) ^ ((lane >> 3) & 3))) << 3);
        const int vd = wave * 8 + (lane >> 3);
        const u16* vg = vbh + (size_t)vd * 2048 + (((lane & 7) ^ (vd & 7)) << 3);

#define GLDS(SRC, DST) __builtin_amdgcn_global_load_lds(                         \
        (const __attribute__((address_space(1))) void*)(SRC),                    \
        (__attribute__((address_space(3))) void*)(DST), 16, 0, 0)
#define DMA(BUF, PAIR) do {                                                      \
    GLDS(kg + (PAIR) * 4096,        KB(BUF, 0) + wave * 512);                    \
    GLDS(kg + (PAIR) * 4096 + 2048, KB(BUF, 1) + wave * 512);                    \
    GLDS(vg + (PAIR) * 128,         VB(BUF, 0) + wave * 512);                    \
    GLDS(vg + (PAIR) * 128 + 64,    VB(BUF, 1) + wave * 512);                    \
} while (0)

        DMA(0, 0);  // pair 0 in flight during setup

        const float* gtab = stab + qt * 128;  // prescaled bias window (L1-hot)

        const int qr0 = qt * 128 + wave * 32 + ql;
        bf16x8 qf[2];
        qf[0] = *(const bf16x8*)(q + ((size_t)bh * 2048 + qr0) * 32 + quad * 8);
        qf[1] = *(const bf16x8*)(q + ((size_t)bh * 2048 + qr0 + 16) * 32 + quad * 8);
        const int bloc0 = wave * 32 + ql + 2047 - quad * 4;
        const int kro = ((quad ^ ((ql >> 1) & 3)) << 3);    // K read swizzle offset

        bf16x4 ones4;
#pragma unroll
        for (int i = 0; i < 4; ++i) ones4[i] = (short)0x3F80;  // bf16 1.0

        f32x4 oT0[2], oT1[2], oL[2];
#pragma unroll
        for (int qh = 0; qh < 2; ++qh) {
            oT0[qh] = (f32x4){0.f, 0.f, 0.f, 0.f};
            oT1[qh] = (f32x4){0.f, 0.f, 0.f, 0.f};
            oL[qh]  = (f32x4){0.f, 0.f, 0.f, 0.f};
        }

        __syncthreads();  // pair 0 landed

        for (int pr = 0; pr < 16; ++pr) {
            const int buf = pr & 1;

            // bias C-fragments for both tiles: 40 dword gathers from the L1-hot
            // window, matching the S^T C/D layout (col=ql, row=quad*4+r).
            f32x4 bc[2][5];
#pragma unroll
            for (int t = 0; t < 2; ++t) {
                const int bkt = bloc0 - (pr * 2 + t) * 64;
#pragma unroll
                for (int g = 0; g < 5; ++g) {
                    const float* p = gtab + (bkt + 16 * g - 51);
                    bc[t][g] = (f32x4){p[3], p[2], p[1], p[0]};
                }
            }
            __builtin_amdgcn_sched_barrier(0);  // bias loads BEFORE the DMA issue

            if (pr < 15) DMA(buf ^ 1, pr + 1);  // lands during this 2-tile body

#pragma unroll
            for (int t = 0; t < 2; ++t) {
                const u16* kb = KB(buf, t);
                const u16* vb = VB(buf, t);
                bf16x8 kf[4];
                bf16x4 va[2][4];  // [d-tile][j]: A-frag of V^T, k = quad*4 + reg
#pragma unroll
                for (int j = 0; j < 4; ++j)
                    kf[j] = *(const bf16x8*)(kb + (j * 16 + ql) * 32 + kro);
#pragma unroll
                for (int dt = 0; dt < 2; ++dt)
#pragma unroll
                    for (int j = 0; j < 4; ++j) {
                        int nloc = j * 16 + quad * 4;           // n-local base of this A-frag
                        int slot = (nloc >> 3) ^ (ql & 7);      // V chunk swizzle
                        va[dt][j] = *(const bf16x4*)(vb + (dt * 16 + ql) * 64 +
                                                     slot * 8 + (nloc & 7));
                    }

#pragma unroll
                for (int qh = 0; qh < 2; ++qh) {
                    f32x4 s[4];
#pragma unroll
                    for (int j = 0; j < 4; ++j)
                        s[j] = MFMA16(kf[j], qf[qh], bc[t][qh + 3 - j]);  // bias via C
#pragma unroll
                    for (int j = 0; j < 4; ++j)
#pragma unroll
                        for (int r = 0; r < 4; ++r)
                            s[j][r] = hw_exp2(s[j][r]);
#pragma unroll
                    for (int j = 0; j < 4; ++j) {
                        union { u32 u[2]; bf16x4 v; } pj;
                        pj.u[0] = __builtin_amdgcn_perm(__float_as_uint(s[j][1]),
                                                        __float_as_uint(s[j][0]), 0x07060302u);
                        pj.u[1] = __builtin_amdgcn_perm(__float_as_uint(s[j][3]),
                                                        __float_as_uint(s[j][2]), 0x07060302u);
                        oT0[qh] = MFMAK16(va[0][j], pj.v, oT0[qh]);
                        oT1[qh] = MFMAK16(va[1][j], pj.v, oT1[qh]);
                        oL[qh]  = MFMAK16(ones4, pj.v, oL[qh]);
                    }
                }
            }
            __syncthreads();  // buf reads done; next DMA drained
        }
#undef DMA
#undef GLDS
#undef KB
#undef VB

        // epilogue: every oL reg holds l for q-col=ql; no shuffles needed
#pragma unroll
        for (int qh = 0; qh < 2; ++qh) {
            float inv = 1.0f / oL[qh][0];
            size_t base = ((size_t)bh * 2048 + qr0 + qh * 16) * 32;
#pragma unroll
            for (int dt = 0; dt < 2; ++dt) {
                const f32x4& o = dt ? oT1[qh] : oT0[qh];
                u16 e0 = f2bf(o[0] * inv), e1 = f2bf(o[1] * inv);
                u16 e2 = f2bf(o[2] * inv), e3 = f2bf(o[3] * inv);
                uint2 pp; pp.x = e0 | ((u32)e1 << 16); pp.y = e2 | ((u32)e3 << 16);
                *(uint2*)(att + base + dt * 16 + quad * 4) = pp;
            }
        }
    }
    grid_barrier(bar, 2);

    // ================= P3: out = att @ w_out + b_out (512 units, 128x32 tiles) =================
    {
        const int bx = bid & 63, by = bid >> 6;  // by in [0,8)
        const int mbase = bx * 128 + (wave & 1) * 64;
        const int nb = by * 32 + (wave >> 1) * 16;
        f32x4 acc[4];
#pragma unroll
        for (int i = 0; i < 4; ++i) acc[i] = (f32x4){0.f, 0.f, 0.f, 0.f};
#pragma unroll
        for (int ks = 0; ks < 8; ++ks) {
            bf16x8 af[4], bfm;
#pragma unroll
            for (int ms = 0; ms < 4; ++ms) {
                int row = mbase + ms * 16 + ql;
                af[ms] = *(const bf16x8*)(qkv +
                    ((size_t)((row >> 11) * 8 + ks) * 2048 + (row & 2047)) * 32 + quad * 8);
            }
            bfm = *(const bf16x8*)(woutT + (size_t)(nb + ql) * 256 + ks * 32 + quad * 8);
#pragma unroll
            for (int ms = 0; ms < 4; ++ms)
                acc[ms] = MFMA16(af[ms], bfm, acc[ms]);
        }
        const float bo = bout[nb + ql];
#pragma unroll
        for (int ms = 0; ms < 4; ++ms)
#pragma unroll
            for (int r = 0; r < 4; ++r) {
                int Mrow = mbase + ms * 16 + quad * 4 + r;
                out[(size_t)Mrow * 256 + (nb + ql)] = acc[ms][r] + bo;
            }
    }
}

extern "C" void kernel_launch(void* const* d_in, const int* in_sizes, int n_in,
                              void* d_out, int out_size, void* d_ws, size_t ws_size,
                              hipStream_t stream) {
    const float* x    = (const float*)d_in[0];  // [4,2048,256] fp32
    const float* wqkv = (const float*)d_in[1];  // [256,768] fp32
    const float* btab = (const float*)d_in[2];  // [16384,1] fp32
    const float* wout = (const float*)d_in[3];  // [256,256] fp32
    const float* bout = (const float*)d_in[4];  // [256] fp32
    // d_in[5] relative_pos is Toeplitz (i - j + 2047) -- computed analytically, not read.
    float* out = (float*)d_out;                 // [4,2048,256] fp32

    // ws layout (bytes): [wqkvT 393216][woutT 131072][qkv 12582912][stab 65536][bar 64]
    if (ws_size < (size_t)13172800) return;
    u16* ws = (u16*)d_ws;
    u16* wqkvT = ws;                        // 196,608 bf16  [768][256]
    u16* woutT = wqkvT + 196608;            // 65,536 bf16   [256][256]
    u16* qkv   = woutT + 65536;             // Q | K | V^T
    float* stab = (float*)(qkv + 6291456);  // 16384 fp32: bias_table * log2(e)
    u32* bar   = (u32*)((char*)d_ws + 13172736);  // 16 u32 barrier slots
    u16* xb    = (u16*)d_out;               // bf16 scratch in d_out; consumed in P1

    hipMemsetAsync(bar, 0, 64, stream);     // zero barrier counters (capture-legal)
    hipLaunchKernelGGL(k_fused, dim3(512), dim3(256), 0, stream,
                       x, wqkv, btab, wout, bout, out,
                       wqkvT, woutT, qkv, stab, xb, bar);
}

// Round 3
// 284.782 us; speedup vs baseline: 1.0155x; 1.0155x over previous
//
#include <hip/hip_runtime.h>

typedef unsigned short u16;
typedef unsigned int u32;
typedef __attribute__((ext_vector_type(8))) short bf16x8;
typedef __attribute__((ext_vector_type(4))) short bf16x4;
typedef __attribute__((ext_vector_type(4))) float f32x4;

#define MFMA16(a, b, c) __builtin_amdgcn_mfma_f32_16x16x32_bf16(a, b, c, 0, 0, 0)
// K=16 bf16 MFMA (gfx90a-lineage "_1k" builtin, valid on gfx950 per ISA §10).
#define MFMAK16(a, b, c) __builtin_amdgcn_mfma_f32_16x16x16bf16_1k(a, b, c, 0, 0, 0)

__device__ __forceinline__ float hw_exp2(float x) { return __builtin_amdgcn_exp2f(x); }

__device__ __forceinline__ u16 f2bf(float f) {
    union { float f; u32 i; } v; v.f = f;
    u32 x = v.i;
    return (u16)((x + 0x7FFFu + ((x >> 16) & 1u)) >> 16);
}

// Device-scope grid barrier. Safe: grid(512) x __launch_bounds__(256,2) => 2 blocks/CU
// x 256 CUs co-resident. ROUND-3 FIX: poll with an agent-scope atomic LOAD (not an
// RMW) + s_sleep backoff. The round-2 version polled with atomicAdd(...,0): 512
// spinning RMWs serialized on one LLC line and queued AHEAD of the arrival
// increments -> ~50us per barrier (all pipes idle in counters). Loads don't
// serialize at the LLC atomic unit and don't block the increments.
__device__ __forceinline__ void grid_barrier(u32* bar, int slot) {
    __syncthreads();
    if (threadIdx.x == 0) {
        __threadfence();                 // release: this block's stores visible
        __hip_atomic_fetch_add(&bar[slot], 1u, __ATOMIC_RELAXED, __HIP_MEMORY_SCOPE_AGENT);
        while (__hip_atomic_load(&bar[slot], __ATOMIC_RELAXED, __HIP_MEMORY_SCOPE_AGENT) < 512u)
            __builtin_amdgcn_s_sleep(32);   // ~2048 cyc backoff between polls
        __threadfence();                 // acquire: see all other blocks' stores
    }
    __syncthreads();
}

// ---------------- fused persistent kernel: prep -> qkv -> attn -> out ----------------
__global__ __launch_bounds__(256, 2) void k_fused(
    const float* __restrict__ x, const float* __restrict__ wqkv,
    const float* __restrict__ btab, const float* __restrict__ wout,
    const float* __restrict__ bout, float* __restrict__ out,
    u16* __restrict__ wqkvT, u16* __restrict__ woutT,
    u16* __restrict__ qkv, float* __restrict__ stab,
    u16* __restrict__ xb, u32* __restrict__ bar) {

    __shared__ __align__(16) u16 smem[16384];  // 32 KB, unioned across phases
    const int bid = blockIdx.x, tid = threadIdx.x;
    const int wave = tid >> 6, lane = tid & 63, quad = lane >> 4, ql = lane & 15;

    // ================= P0: prep (2112 virtual units over 512 blocks) =================
    {
        const float QSCALE2 = 0.2550566756538019f;  // 32^-0.5 * log2(e)
        const float LOG2E = 1.4426950408889634f;
        for (int u = bid; u < 2112; u += 512) {
            if (u < 1024) {
                int base = u * 2048 + tid * 8;
                float4 a = *(const float4*)(x + base);
                float4 b = *(const float4*)(x + base + 4);
                uint4 r;
                r.x = f2bf(a.x) | ((u32)f2bf(a.y) << 16);
                r.y = f2bf(a.z) | ((u32)f2bf(a.w) << 16);
                r.z = f2bf(b.x) | ((u32)f2bf(b.y) << 16);
                r.w = f2bf(b.z) | ((u32)f2bf(b.w) << 16);
                *(uint4*)(xb + base) = r;
            } else if (u < 1792) {
                int idx = (u - 1024) * 256 + tid;
                int n = idx >> 8, kk = idx & 255;
                float sc = (n < 256) ? QSCALE2 : 1.0f;
                wqkvT[idx] = f2bf(wqkv[kk * 768 + n] * sc);
            } else if (u < 2048) {
                int idx = (u - 1792) * 256 + tid;
                int n = idx >> 8, kk = idx & 255;
                woutT[idx] = f2bf(wout[kk * 256 + n]);
            } else {
                int idx = (u - 2048) * 256 + tid;  // < 16384
                stab[idx] = btab[idx] * LOG2E;
            }
        }
    }
    grid_barrier(bar, 0);

    // ================= P1: qkv = xb @ w_qkv (768 units, 2 rounds) =================
    for (int u = bid; u < 768; u += 512) {
        const int bx = u & 63, by = u >> 6;
        u16* slds = smem;  // [128][68] or [64][136]
        const int mbase = bx * 128 + (wave & 1) * 64;
        const int nbase = by * 64 + (wave >> 1) * 32;
        f32x4 acc[4][2];
#pragma unroll
        for (int i = 0; i < 4; ++i)
#pragma unroll
            for (int j = 0; j < 2; ++j) acc[i][j] = (f32x4){0.f, 0.f, 0.f, 0.f};
#pragma unroll
        for (int ks = 0; ks < 8; ++ks) {
            bf16x8 af[4], bfm[2];
#pragma unroll
            for (int ms = 0; ms < 4; ++ms)
                af[ms] = *(const bf16x8*)(xb + (size_t)(mbase + ms * 16 + ql) * 256 + ks * 32 + quad * 8);
#pragma unroll
            for (int ns = 0; ns < 2; ++ns)
                bfm[ns] = *(const bf16x8*)(wqkvT + (size_t)(nbase + ns * 16 + ql) * 256 + ks * 32 + quad * 8);
#pragma unroll
            for (int ms = 0; ms < 4; ++ms)
#pragma unroll
                for (int ns = 0; ns < 2; ++ns)
                    acc[ms][ns] = MFMA16(af[ms], bfm[ns], acc[ms][ns]);
        }

        const int t = (by * 64) >> 8;  // 0=Q, 1=K, 2=V (uniform per unit)
        if (t < 2) {
            const int rowb = (wave & 1) * 64, colb = (wave >> 1) * 32;
#pragma unroll
            for (int ms = 0; ms < 4; ++ms)
#pragma unroll
                for (int ns = 0; ns < 2; ++ns)
#pragma unroll
                    for (int r = 0; r < 4; ++r)
                        slds[(rowb + ms * 16 + quad * 4 + r) * 68 + colb + ns * 16 + ql] =
                            f2bf(acc[ms][ns][r]);
            __syncthreads();
            u16* base = qkv + (size_t)t * 2097152;
#pragma unroll
            for (int p = 0; p < 8; ++p) {
                int c = p * 256 + tid;
                int row = c >> 4, ch = c & 15;
                uint2 w = *(const uint2*)&slds[row * 68 + ch * 4];
                int n = bx * 128 + row;
                int col = by * 64 + ch * 4;
                int h = (col & 255) >> 5, d = col & 31;
                *(uint2*)(base + ((size_t)((n >> 11) * 8 + h) * 2048 + (n & 2047)) * 32 + d) = w;
            }
        } else {
            const int hl = wave >> 1, nb = (wave & 1) * 64;
#pragma unroll
            for (int ms = 0; ms < 4; ++ms)
#pragma unroll
                for (int ns = 0; ns < 2; ++ns) {
                    u16 e0 = f2bf(acc[ms][ns][0]), e1 = f2bf(acc[ms][ns][1]);
                    u16 e2 = f2bf(acc[ms][ns][2]), e3 = f2bf(acc[ms][ns][3]);
                    uint2 pp; pp.x = e0 | ((u32)e1 << 16); pp.y = e2 | ((u32)e3 << 16);
                    *(uint2*)&slds[(hl * 32 + ns * 16 + ql) * 136 + nb + ms * 16 + quad * 4] = pp;
                }
            __syncthreads();
            u16* vbase = qkv + (size_t)2 * 2097152;
#pragma unroll
            for (int p = 0; p < 4; ++p) {
                int c = p * 256 + tid;
                int row = c >> 4, ch = c & 15;
                bf16x8 w = *(const bf16x8*)&slds[row * 136 + ch * 8];
                int n0 = bx * 128 + ch * 8;
                int h = (by & 3) * 2 + (row >> 5), d = row & 31;
                *(bf16x8*)(vbase + (size_t)((n0 >> 11) * 8 + h) * 65536 +
                           (size_t)d * 2048 + (n0 & 2047)) = w;
            }
        }
        __syncthreads();  // protect slds before next unit reuses it
    }
    grid_barrier(bar, 1);

    // ================= P2: flash attention (exactly 512 blocks) =================
    {
        const u16* q = qkv;
        const u16* k = qkv + 2097152;
        const u16* vT = qkv + 2 * 2097152;
        u16* att = qkv;  // overwrite Q region in place
        const int bh = bid & 31, qt = bid >> 5;

        // smem union: kbuf = smem[0..8191], vbuf = smem[8192..16383]
#define KB(BUF, T) (smem + (BUF) * 4096 + (T) * 2048)
#define VB(BUF, T) (smem + 8192 + (BUF) * 4096 + (T) * 2048)

        const u16* kbh = k + (size_t)bh * 65536;
        const u16* vbh = vT + (size_t)bh * 65536;  // [32 d][2048 n]

        const int krow = wave * 16 + (lane >> 2);
        const u16* kg = kbh + krow * 32 + ((((lane & 3) ^ ((lane >> 3) & 3))) << 3);
        const int vd = wave * 8 + (lane >> 3);
        const u16* vg = vbh + (size_t)vd * 2048 + (((lane & 7) ^ (vd & 7)) << 3);

#define GLDS(SRC, DST) __builtin_amdgcn_global_load_lds(                         \
        (const __attribute__((address_space(1))) void*)(SRC),                    \
        (__attribute__((address_space(3))) void*)(DST), 16, 0, 0)
#define DMA(BUF, PAIR) do {                                                      \
    GLDS(kg + (PAIR) * 4096,        KB(BUF, 0) + wave * 512);                    \
    GLDS(kg + (PAIR) * 4096 + 2048, KB(BUF, 1) + wave * 512);                    \
    GLDS(vg + (PAIR) * 128,         VB(BUF, 0) + wave * 512);                    \
    GLDS(vg + (PAIR) * 128 + 64,    VB(BUF, 1) + wave * 512);                    \
} while (0)

        DMA(0, 0);  // pair 0 in flight during setup

        const float* gtab = stab + qt * 128;  // prescaled bias window (L1-hot)

        const int qr0 = qt * 128 + wave * 32 + ql;
        bf16x8 qf[2];
        qf[0] = *(const bf16x8*)(q + ((size_t)bh * 2048 + qr0) * 32 + quad * 8);
        qf[1] = *(const bf16x8*)(q + ((size_t)bh * 2048 + qr0 + 16) * 32 + quad * 8);
        const int bloc0 = wave * 32 + ql + 2047 - quad * 4;
        const int kro = ((quad ^ ((ql >> 1) & 3)) << 3);    // K read swizzle offset

        bf16x4 ones4;
#pragma unroll
        for (int i = 0; i < 4; ++i) ones4[i] = (short)0x3F80;  // bf16 1.0

        f32x4 oT0[2], oT1[2], oL[2];
#pragma unroll
        for (int qh = 0; qh < 2; ++qh) {
            oT0[qh] = (f32x4){0.f, 0.f, 0.f, 0.f};
            oT1[qh] = (f32x4){0.f, 0.f, 0.f, 0.f};
            oL[qh]  = (f32x4){0.f, 0.f, 0.f, 0.f};
        }

        __syncthreads();  // pair 0 landed

        for (int pr = 0; pr < 16; ++pr) {
            const int buf = pr & 1;

            // bias C-fragments for both tiles: 40 dword gathers from the L1-hot
            // window, matching the S^T C/D layout (col=ql, row=quad*4+r).
            f32x4 bc[2][5];
#pragma unroll
            for (int t = 0; t < 2; ++t) {
                const int bkt = bloc0 - (pr * 2 + t) * 64;
#pragma unroll
                for (int g = 0; g < 5; ++g) {
                    const float* p = gtab + (bkt + 16 * g - 51);
                    bc[t][g] = (f32x4){p[3], p[2], p[1], p[0]};
                }
            }
            __builtin_amdgcn_sched_barrier(0);  // bias loads BEFORE the DMA issue

            if (pr < 15) DMA(buf ^ 1, pr + 1);  // lands during this 2-tile body

#pragma unroll
            for (int t = 0; t < 2; ++t) {
                const u16* kb = KB(buf, t);
                const u16* vb = VB(buf, t);
                bf16x8 kf[4];
                bf16x4 va[2][4];  // [d-tile][j]: A-frag of V^T, k = quad*4 + reg
#pragma unroll
                for (int j = 0; j < 4; ++j)
                    kf[j] = *(const bf16x8*)(kb + (j * 16 + ql) * 32 + kro);
#pragma unroll
                for (int dt = 0; dt < 2; ++dt)
#pragma unroll
                    for (int j = 0; j < 4; ++j) {
                        int nloc = j * 16 + quad * 4;           // n-local base of this A-frag
                        int slot = (nloc >> 3) ^ (ql & 7);      // V chunk swizzle
                        va[dt][j] = *(const bf16x4*)(vb + (dt * 16 + ql) * 64 +
                                                     slot * 8 + (nloc & 7));
                    }

#pragma unroll
                for (int qh = 0; qh < 2; ++qh) {
                    f32x4 s[4];
#pragma unroll
                    for (int j = 0; j < 4; ++j)
                        s[j] = MFMA16(kf[j], qf[qh], bc[t][qh + 3 - j]);  // bias via C
#pragma unroll
                    for (int j = 0; j < 4; ++j)
#pragma unroll
                        for (int r = 0; r < 4; ++r)
                            s[j][r] = hw_exp2(s[j][r]);
#pragma unroll
                    for (int j = 0; j < 4; ++j) {
                        union { u32 u[2]; bf16x4 v; } pj;
                        pj.u[0] = __builtin_amdgcn_perm(__float_as_uint(s[j][1]),
                                                        __float_as_uint(s[j][0]), 0x07060302u);
                        pj.u[1] = __builtin_amdgcn_perm(__float_as_uint(s[j][3]),
                                                        __float_as_uint(s[j][2]), 0x07060302u);
                        oT0[qh] = MFMAK16(va[0][j], pj.v, oT0[qh]);
                        oT1[qh] = MFMAK16(va[1][j], pj.v, oT1[qh]);
                        oL[qh]  = MFMAK16(ones4, pj.v, oL[qh]);
                    }
                }
            }
            __syncthreads();  // buf reads done; next DMA drained
        }
#undef DMA
#undef GLDS
#undef KB
#undef VB

        // epilogue: every oL reg holds l for q-col=ql; no shuffles needed
#pragma unroll
        for (int qh = 0; qh < 2; ++qh) {
            float inv = 1.0f / oL[qh][0];
            size_t base = ((size_t)bh * 2048 + qr0 + qh * 16) * 32;
#pragma unroll
            for (int dt = 0; dt < 2; ++dt) {
                const f32x4& o = dt ? oT1[qh] : oT0[qh];
                u16 e0 = f2bf(o[0] * inv), e1 = f2bf(o[1] * inv);
                u16 e2 = f2bf(o[2] * inv), e3 = f2bf(o[3] * inv);
                uint2 pp; pp.x = e0 | ((u32)e1 << 16); pp.y = e2 | ((u32)e3 << 16);
                *(uint2*)(att + base + dt * 16 + quad * 4) = pp;
            }
        }
    }
    grid_barrier(bar, 2);

    // ================= P3: out = att @ w_out + b_out (512 units, 128x32 tiles) =================
    {
        const int bx = bid & 63, by = bid >> 6;  // by in [0,8)
        const int mbase = bx * 128 + (wave & 1) * 64;
        const int nb = by * 32 + (wave >> 1) * 16;
        f32x4 acc[4];
#pragma unroll
        for (int i = 0; i < 4; ++i) acc[i] = (f32x4){0.f, 0.f, 0.f, 0.f};
#pragma unroll
        for (int ks = 0; ks < 8; ++ks) {
            bf16x8 af[4], bfm;
#pragma unroll
            for (int ms = 0; ms < 4; ++ms) {
                int row = mbase + ms * 16 + ql;
                af[ms] = *(const bf16x8*)(qkv +
                    ((size_t)((row >> 11) * 8 + ks) * 2048 + (row & 2047)) * 32 + quad * 8);
            }
            bfm = *(const bf16x8*)(woutT + (size_t)(nb + ql) * 256 + ks * 32 + quad * 8);
#pragma unroll
            for (int ms = 0; ms < 4; ++ms)
                acc[ms] = MFMA16(af[ms], bfm, acc[ms]);
        }
        const float bo = bout[nb + ql];
#pragma unroll
        for (int ms = 0; ms < 4; ++ms)
#pragma unroll
            for (int r = 0; r < 4; ++r) {
                int Mrow = mbase + ms * 16 + quad * 4 + r;
                out[(size_t)Mrow * 256 + (nb + ql)] = acc[ms][r] + bo;
            }
    }
}

extern "C" void kernel_launch(void* const* d_in, const int* in_sizes, int n_in,
                              void* d_out, int out_size, void* d_ws, size_t ws_size,
                              hipStream_t stream) {
    const float* x    = (const float*)d_in[0];  // [4,2048,256] fp32
    const float* wqkv = (const float*)d_in[1];  // [256,768] fp32
    const float* btab = (const float*)d_in[2];  // [16384,1] fp32
    const float* wout = (const float*)d_in[3];  // [256,256] fp32
    const float* bout = (const float*)d_in[4];  // [256] fp32
    // d_in[5] relative_pos is Toeplitz (i - j + 2047) -- computed analytically, not read.
    float* out = (float*)d_out;                 // [4,2048,256] fp32

    // ws layout (bytes): [wqkvT 393216][woutT 131072][qkv 12582912][stab 65536][bar 64]
    if (ws_size < (size_t)13172800) return;
    u16* ws = (u16*)d_ws;
    u16* wqkvT = ws;                        // 196,608 bf16  [768][256]
    u16* woutT = wqkvT + 196608;            // 65,536 bf16   [256][256]
    u16* qkv   = woutT + 65536;             // Q | K | V^T
    float* stab = (float*)(qkv + 6291456);  // 16384 fp32: bias_table * log2(e)
    u32* bar   = (u32*)((char*)d_ws + 13172736);  // 16 u32 barrier slots
    u16* xb    = (u16*)d_out;               // bf16 scratch in d_out; consumed in P1

    hipMemsetAsync(bar, 0, 64, stream);     // zero barrier counters (capture-legal)
    hipLaunchKernelGGL(k_fused, dim3(512), dim3(256), 0, stream,
                       x, wqkv, btab, wout, bout, out,
                       wqkvT, woutT, qkv, stab, xb, bar);
}

// Round 4
// 143.494 us; speedup vs baseline: 2.0154x; 1.9846x over previous
//
#include <hip/hip_runtime.h>

typedef unsigned short u16;
typedef unsigned int u32;
typedef __attribute__((ext_vector_type(8))) short bf16x8;
typedef __attribute__((ext_vector_type(4))) short bf16x4;
typedef __attribute__((ext_vector_type(4))) float f32x4;

#define MFMA16(a, b, c) __builtin_amdgcn_mfma_f32_16x16x32_bf16(a, b, c, 0, 0, 0)
// K=16 bf16 MFMA (gfx90a-lineage "_1k" builtin, valid on gfx950 per ISA §10).
#define MFMAK16(a, b, c) __builtin_amdgcn_mfma_f32_16x16x16bf16_1k(a, b, c, 0, 0, 0)

__device__ __forceinline__ float hw_exp2(float x) { return __builtin_amdgcn_exp2f(x); }

__device__ __forceinline__ u16 f2bf(float f) {
    union { float f; u32 i; } v; v.f = f;
    u32 x = v.i;
    return (u16)((x + 0x7FFFu + ((x >> 16) & 1u)) >> 16);
}

__device__ __forceinline__ bf16x8 pack8(float4 a, float4 b) {
    bf16x8 r;
    r[0] = (short)f2bf(a.x); r[1] = (short)f2bf(a.y);
    r[2] = (short)f2bf(a.z); r[3] = (short)f2bf(a.w);
    r[4] = (short)f2bf(b.x); r[5] = (short)f2bf(b.y);
    r[6] = (short)f2bf(b.z); r[7] = (short)f2bf(b.w);
    return r;
}

// ---------------- kernel 1: qkv = bf16(x) @ bf16(w_qkv), inline conversion ----------------
// prep eliminated: A-fragments packed from fp32 x on the fly; the block's 64-col
// wqkv slice (scaled for Q) is converted once into a 16B-aligned LDS tile.
__global__ __launch_bounds__(256) void k_gemm_qkv(const float* __restrict__ x,
                                                  const float* __restrict__ wqkv,
                                                  u16* __restrict__ qkv) {
    __shared__ __align__(16) u16 smem[16896];  // B-tile [64][264] (33 KB); epilogue reuses 8704
    const int tid = threadIdx.x;
    const int wave = tid >> 6, lane = tid & 63, quad = lane >> 4, ql = lane & 15;
    const int by = blockIdx.y;
    const int mbase = blockIdx.x * 128 + (wave & 1) * 64;
    const float QSCALE2 = 0.2550566756538019f;  // 32^-0.5 * log2(e)

    // stage B slice: wqkv cols [by*64, by*64+64), all 256 k, transposed to [n][k] bf16
    {
        const int c4 = (tid & 15) * 4;
        const float sc = (by < 4) ? QSCALE2 : 1.0f;  // Q = first 256 out-cols (by 0..3)
        for (int kk = tid >> 4; kk < 256; kk += 16) {
            float4 w4 = *(const float4*)(wqkv + (size_t)kk * 768 + by * 64 + c4);
            smem[(c4 + 0) * 264 + kk] = f2bf(w4.x * sc);
            smem[(c4 + 1) * 264 + kk] = f2bf(w4.y * sc);
            smem[(c4 + 2) * 264 + kk] = f2bf(w4.z * sc);
            smem[(c4 + 3) * 264 + kk] = f2bf(w4.w * sc);
        }
    }
    __syncthreads();

    const int nrow = (wave >> 1) * 32;  // n-local base of this wave
    f32x4 acc[4][2];
#pragma unroll
    for (int i = 0; i < 4; ++i)
#pragma unroll
        for (int j = 0; j < 2; ++j) acc[i][j] = (f32x4){0.f, 0.f, 0.f, 0.f};
#pragma unroll
    for (int ks = 0; ks < 8; ++ks) {
        bf16x8 af[4], bfm[2];
#pragma unroll
        for (int ms = 0; ms < 4; ++ms) {
            const float* ap = x + (size_t)(mbase + ms * 16 + ql) * 256 + ks * 32 + quad * 8;
            af[ms] = pack8(*(const float4*)ap, *(const float4*)(ap + 4));
        }
#pragma unroll
        for (int ns = 0; ns < 2; ++ns)
            bfm[ns] = *(const bf16x8*)&smem[(nrow + ns * 16 + ql) * 264 + ks * 32 + quad * 8];
#pragma unroll
        for (int ms = 0; ms < 4; ++ms)
#pragma unroll
            for (int ns = 0; ns < 2; ++ns)
                acc[ms][ns] = MFMA16(af[ms], bfm[ns], acc[ms][ns]);
    }
    __syncthreads();  // B-tile reads done before epilogue reuses smem

    u16* slds = smem;
    const int t = (by * 64) >> 8;  // 0=Q, 1=K, 2=V (uniform per block)
    if (t < 2) {
        const int rowb = (wave & 1) * 64, colb = (wave >> 1) * 32;
#pragma unroll
        for (int ms = 0; ms < 4; ++ms)
#pragma unroll
            for (int ns = 0; ns < 2; ++ns)
#pragma unroll
                for (int r = 0; r < 4; ++r)
                    slds[(rowb + ms * 16 + quad * 4 + r) * 68 + colb + ns * 16 + ql] =
                        f2bf(acc[ms][ns][r]);
        __syncthreads();
        u16* base = qkv + (size_t)t * 2097152;
#pragma unroll
        for (int p = 0; p < 8; ++p) {
            int c = p * 256 + tid;
            int row = c >> 4, ch = c & 15;
            uint2 w = *(const uint2*)&slds[row * 68 + ch * 4];
            int n = blockIdx.x * 128 + row;
            int col = by * 64 + ch * 4;
            int h = (col & 255) >> 5, d = col & 31;
            *(uint2*)(base + ((size_t)((n >> 11) * 8 + h) * 2048 + (n & 2047)) * 32 + d) = w;
        }
    } else {
        const int hl = wave >> 1, nb = (wave & 1) * 64;
#pragma unroll
        for (int ms = 0; ms < 4; ++ms)
#pragma unroll
            for (int ns = 0; ns < 2; ++ns) {
                u16 e0 = f2bf(acc[ms][ns][0]), e1 = f2bf(acc[ms][ns][1]);
                u16 e2 = f2bf(acc[ms][ns][2]), e3 = f2bf(acc[ms][ns][3]);
                uint2 pp; pp.x = e0 | ((u32)e1 << 16); pp.y = e2 | ((u32)e3 << 16);
                *(uint2*)&slds[(hl * 32 + ns * 16 + ql) * 136 + nb + ms * 16 + quad * 4] = pp;
            }
        __syncthreads();
        u16* vbase = qkv + (size_t)2 * 2097152;
#pragma unroll
        for (int p = 0; p < 4; ++p) {
            int c = p * 256 + tid;
            int row = c >> 4, ch = c & 15;
            bf16x8 w = *(const bf16x8*)&slds[row * 136 + ch * 8];
            int n0 = blockIdx.x * 128 + ch * 8;
            int h = (by & 3) * 2 + (row >> 5), d = row & 31;
            *(bf16x8*)(vbase + (size_t)((n0 >> 11) * 8 + h) * 65536 +
                       (size_t)d * 2048 + (n0 & 2047)) = w;
        }
    }
}

// ---------------- kernel 2: flash attention, DMA K/V, register P --------------
// grid 512: bh = bx&31, qt = bx>>5. Block 4 waves; wave = 32 q-rows (2 qh).
// KEY IDENTITY: mfma_f32_16x16x16_bf16's B-fragment (n=ql, k=quad*4+reg) == the C/D layout
// of the S^T tiles (col=ql, row=quad*4+r). So P^T feeds PV straight from registers.
// Bias: staged per-block into LDS from btab (scaled by log2e) -- the original proven
// path -- and fed into the QK^T MFMA C-operand (round-1's trick, LDS-sourced).
__global__ __launch_bounds__(256, 2) void k_attn(const u16* __restrict__ q,
                                                 const u16* __restrict__ k,
                                                 const u16* __restrict__ vT,
                                                 const float* __restrict__ table,
                                                 u16* __restrict__ att) {
    __shared__ __align__(16) u16 kbuf[2][2][2048];  // [buf][tile][swizzled 64x32]
    __shared__ __align__(16) u16 vbuf[2][2][2048];  // [buf][tile][32 d][64 n swizzled 8-chunks]
    __shared__ float tbl2[2176];
    const int tid = threadIdx.x;
    const int bh = blockIdx.x & 31, qt = blockIdx.x >> 5;
    const int wave = tid >> 6, lane = tid & 63, quad = lane >> 4, ql = lane & 15;
    const float LOG2E = 1.4426950408889634f;

    const u16* kbh = k + (size_t)bh * 65536;
    const u16* vbh = vT + (size_t)bh * 65536;  // [32 d][2048 n]

    // DMA lane->global maps (LDS side forced contiguous: base + lane*16B).
    const int krow = wave * 16 + (lane >> 2);
    const u16* kg = kbh + krow * 32 + ((((lane & 3) ^ ((lane >> 3) & 3))) << 3);
    const int vd = wave * 8 + (lane >> 3);
    const u16* vg = vbh + (size_t)vd * 2048 + (((lane & 7) ^ (vd & 7)) << 3);

#define GLDS(SRC, DST) __builtin_amdgcn_global_load_lds(                         \
        (const __attribute__((address_space(1))) void*)(SRC),                    \
        (__attribute__((address_space(3))) void*)(DST), 16, 0, 0)
#define DMA(BUF, PAIR) do {                                                      \
    GLDS(kg + (PAIR) * 4096,        &kbuf[BUF][0][wave * 512]);                  \
    GLDS(kg + (PAIR) * 4096 + 2048, &kbuf[BUF][1][wave * 512]);                  \
    GLDS(vg + (PAIR) * 128,         &vbuf[BUF][0][wave * 512]);                  \
    GLDS(vg + (PAIR) * 128 + 64,    &vbuf[BUF][1][wave * 512]);                  \
} while (0)

    DMA(0, 0);  // pair 0 in flight during bias staging

    // bias window: idx = q - kv + 2047 - qt*128 in [0, 2174]
    const float4* tg = (const float4*)(table + qt * 128);
    for (int i = tid; i < 544; i += 256) {
        float4 t = tg[i];
        t.x *= LOG2E; t.y *= LOG2E; t.z *= LOG2E; t.w *= LOG2E;
        ((float4*)tbl2)[i] = t;
    }

    const int qr0 = qt * 128 + wave * 32 + ql;
    bf16x8 qf[2];
    qf[0] = *(const bf16x8*)(q + ((size_t)bh * 2048 + qr0) * 32 + quad * 8);
    qf[1] = *(const bf16x8*)(q + ((size_t)bh * 2048 + qr0 + 16) * 32 + quad * 8);
    const int bloc0 = wave * 32 + ql + 2047 - quad * 4;
    const int kro = ((quad ^ ((ql >> 1) & 3)) << 3);    // K read swizzle offset

    bf16x4 ones4;
#pragma unroll
    for (int i = 0; i < 4; ++i) ones4[i] = (short)0x3F80;  // bf16 1.0

    f32x4 oT0[2], oT1[2], oL[2];
#pragma unroll
    for (int qh = 0; qh < 2; ++qh) {
        oT0[qh] = (f32x4){0.f, 0.f, 0.f, 0.f};
        oT1[qh] = (f32x4){0.f, 0.f, 0.f, 0.f};
        oL[qh]  = (f32x4){0.f, 0.f, 0.f, 0.f};
    }

    __syncthreads();  // bias + pair 0 ready

    for (int pr = 0; pr < 16; ++pr) {
        const int buf = pr & 1;

        // bias C-fragments for both tiles of this pair, from the LDS window.
        // bc[t][g][r] matches the S^T C/D layout (col=ql, row=quad*4+r).
        f32x4 bc[2][5];
#pragma unroll
        for (int t = 0; t < 2; ++t) {
            const int bkt = bloc0 - (pr * 2 + t) * 64;
#pragma unroll
            for (int g = 0; g < 5; ++g) {
                const int b0 = bkt + 16 * g - 51;
                bc[t][g] = (f32x4){tbl2[b0 + 3], tbl2[b0 + 2], tbl2[b0 + 1], tbl2[b0 + 0]};
            }
        }
        __builtin_amdgcn_sched_barrier(0);  // bias reads issue before the DMA

        if (pr < 15) DMA(buf ^ 1, pr + 1);  // lands during this 2-tile body

#pragma unroll
        for (int t = 0; t < 2; ++t) {
            const u16* kb = &kbuf[buf][t][0];
            const u16* vb = &vbuf[buf][t][0];
            bf16x8 kf[4];
            bf16x4 va[2][4];  // [d-tile][j]: A-frag of V^T, k = quad*4 + reg
#pragma unroll
            for (int j = 0; j < 4; ++j)
                kf[j] = *(const bf16x8*)(kb + (j * 16 + ql) * 32 + kro);
#pragma unroll
            for (int dt = 0; dt < 2; ++dt)
#pragma unroll
                for (int j = 0; j < 4; ++j) {
                    int nloc = j * 16 + quad * 4;           // n-local base of this A-frag
                    int slot = (nloc >> 3) ^ (ql & 7);      // V chunk swizzle
                    va[dt][j] = *(const bf16x4*)(vb + (dt * 16 + ql) * 64 +
                                                 slot * 8 + (nloc & 7));
                }

#pragma unroll
            for (int qh = 0; qh < 2; ++qh) {
                f32x4 s[4];
#pragma unroll
                for (int j = 0; j < 4; ++j)
                    s[j] = MFMA16(kf[j], qf[qh], bc[t][qh + 3 - j]);  // bias via C
#pragma unroll
                for (int j = 0; j < 4; ++j)
#pragma unroll
                    for (int r = 0; r < 4; ++r)
                        s[j][r] = hw_exp2(s[j][r]);
#pragma unroll
                for (int j = 0; j < 4; ++j) {
                    union { u32 u[2]; bf16x4 v; } pj;
                    pj.u[0] = __builtin_amdgcn_perm(__float_as_uint(s[j][1]),
                                                    __float_as_uint(s[j][0]), 0x07060302u);
                    pj.u[1] = __builtin_amdgcn_perm(__float_as_uint(s[j][3]),
                                                    __float_as_uint(s[j][2]), 0x07060302u);
                    oT0[qh] = MFMAK16(va[0][j], pj.v, oT0[qh]);
                    oT1[qh] = MFMAK16(va[1][j], pj.v, oT1[qh]);
                    oL[qh]  = MFMAK16(ones4, pj.v, oL[qh]);
                }
            }
        }
        __syncthreads();  // buf reads done; next DMA drained
    }
#undef DMA
#undef GLDS

    // epilogue: every oL reg holds l for q-col=ql; no shuffles needed
#pragma unroll
    for (int qh = 0; qh < 2; ++qh) {
        float inv = 1.0f / oL[qh][0];
        size_t base = ((size_t)bh * 2048 + qr0 + qh * 16) * 32;
#pragma unroll
        for (int dt = 0; dt < 2; ++dt) {
            const f32x4& o = dt ? oT1[qh] : oT0[qh];
            u16 e0 = f2bf(o[0] * inv), e1 = f2bf(o[1] * inv);
            u16 e2 = f2bf(o[2] * inv), e3 = f2bf(o[3] * inv);
            uint2 pp; pp.x = e0 | ((u32)e1 << 16); pp.y = e2 | ((u32)e3 << 16);
            *(uint2*)(att + base + dt * 16 + quad * 4) = pp;
        }
    }
}

// ---------------- kernel 3: out = att @ bf16(w_out) + b_out -> fp32 d_out ----------------
// wout slice converted inline into LDS (prep eliminated).
__global__ __launch_bounds__(256) void k_gemm_out(const u16* __restrict__ attq,
                                                  const float* __restrict__ wout,
                                                  const float* __restrict__ bout,
                                                  float* __restrict__ out) {
    __shared__ __align__(16) u16 bs[16896];  // [64][264] bf16 B-tile
    const int tid = threadIdx.x;
    const int wave = tid >> 6, lane = tid & 63, quad = lane >> 4, ql = lane & 15;
    const int by = blockIdx.y;
    const int mbase = blockIdx.x * 128 + (wave & 1) * 64;

    {
        const int c4 = (tid & 15) * 4;
        for (int kk = tid >> 4; kk < 256; kk += 16) {
            float4 w4 = *(const float4*)(wout + (size_t)kk * 256 + by * 64 + c4);
            bs[(c4 + 0) * 264 + kk] = f2bf(w4.x);
            bs[(c4 + 1) * 264 + kk] = f2bf(w4.y);
            bs[(c4 + 2) * 264 + kk] = f2bf(w4.z);
            bs[(c4 + 3) * 264 + kk] = f2bf(w4.w);
        }
    }
    __syncthreads();

    const int nrow = (wave >> 1) * 32;
    f32x4 acc[4][2];
#pragma unroll
    for (int i = 0; i < 4; ++i)
#pragma unroll
        for (int j = 0; j < 2; ++j) acc[i][j] = (f32x4){0.f, 0.f, 0.f, 0.f};
#pragma unroll
    for (int ks = 0; ks < 8; ++ks) {
        bf16x8 af[4], bfm[2];
#pragma unroll
        for (int ms = 0; ms < 4; ++ms) {
            int row = mbase + ms * 16 + ql;
            af[ms] = *(const bf16x8*)(attq +
                ((size_t)((row >> 11) * 8 + ks) * 2048 + (row & 2047)) * 32 + quad * 8);
        }
#pragma unroll
        for (int ns = 0; ns < 2; ++ns)
            bfm[ns] = *(const bf16x8*)&bs[(nrow + ns * 16 + ql) * 264 + ks * 32 + quad * 8];
#pragma unroll
        for (int ms = 0; ms < 4; ++ms)
#pragma unroll
            for (int ns = 0; ns < 2; ++ns)
                acc[ms][ns] = MFMA16(af[ms], bfm[ns], acc[ms][ns]);
    }
#pragma unroll
    for (int ms = 0; ms < 4; ++ms)
#pragma unroll
        for (int ns = 0; ns < 2; ++ns)
#pragma unroll
            for (int r = 0; r < 4; ++r) {
                int Mrow = mbase + ms * 16 + quad * 4 + r;
                int col = by * 64 + (wave >> 1) * 32 + ns * 16 + ql;
                out[(size_t)Mrow * 256 + col] = acc[ms][ns][r] + bout[col];
            }
}

extern "C" void kernel_launch(void* const* d_in, const int* in_sizes, int n_in,
                              void* d_out, int out_size, void* d_ws, size_t ws_size,
                              hipStream_t stream) {
    const float* x    = (const float*)d_in[0];  // [4,2048,256] fp32
    const float* wqkv = (const float*)d_in[1];  // [256,768] fp32
    const float* btab = (const float*)d_in[2];  // [16384,1] fp32
    const float* wout = (const float*)d_in[3];  // [256,256] fp32
    const float* bout = (const float*)d_in[4];  // [256] fp32
    // d_in[5] relative_pos is Toeplitz (i - j + 2047) -- computed analytically, not read.
    float* out = (float*)d_out;                 // [4,2048,256] fp32

    // ws layout: qkv only -- Q [B*H][N][D] | K [B*H][N][D] | V^T [B*H][D][N], bf16
    if (ws_size < (size_t)12582912) return;
    u16* qkv = (u16*)d_ws;

    hipLaunchKernelGGL(k_gemm_qkv, dim3(64, 12), dim3(256), 0, stream, x, wqkv, qkv);
    // k_attn writes its output (bf16, [B*H][N][D]) back into the Q third of qkv.
    hipLaunchKernelGGL(k_attn, dim3(512), dim3(256), 0, stream,
                       qkv, qkv + 2097152, qkv + 2 * 2097152, btab, qkv);
    hipLaunchKernelGGL(k_gemm_out, dim3(64, 4), dim3(256), 0, stream, qkv, wout, bout, out);
}